// Round 11
// baseline (96.576 us; speedup 1.0000x reference)
//
#include <hip/hip_runtime.h>

#define BATCH   8
#define SHAPE_N 8192
#define SKEL_M  2048

// ws layout:
//   uint4[0,      32768): packed skel  frags (16384 pts x 2 uint4)  512 KB
//   uint4[32768, 163840): packed shape frags (65536 pts x 2 uint4)    2 MB
//   then float part1[512]           dir1 per-block partial sums
//   then float part2[4][8][2048]    dir2 partial mins (quarter-major)
// Every slot read is written in the same iteration -> re-poison-safe,
// no init, no atomics.

// MFMA frag types (gfx950: 32x32x16 bf16 — A/B = 8 bf16 (4 VGPRs), C/D = 16 f32)
typedef short bf16x8 __attribute__((ext_vector_type(8)));
typedef float f32x16 __attribute__((ext_vector_type(16)));
union FragU { bf16x8 v; uint4 u4; };

// round-to-nearest-even f32 -> bf16 (result in low 16 bits)
__device__ __forceinline__ unsigned int f2bf(float a) {
    unsigned int u = __float_as_uint(a);
    return (u + 0x7FFFu + ((u >> 16) & 1u)) >> 16;
}
__device__ __forceinline__ float bf2f(unsigned int h) {
    return __uint_as_float(h << 16);
}
__device__ __forceinline__ unsigned int pack2(unsigned int lo, unsigned int hi) {
    return lo | (hi << 16);
}
// v ~= hi + lo (two bf16), residual ~2^-16 relative
__device__ __forceinline__ void bfsplit(float v, unsigned int& h, unsigned int& l) {
    h = f2bf(v);
    l = f2bf(v - bf2f(h));
}

// resident B-operand frag + fp32 |a|^2 for one a-point (same as R7-R10)
__device__ __forceinline__ void make_bfrag(
    const float* __restrict__ ap, int l, FragU& bf, float& ra)
{
    const float x = ap[0], y = ap[1], z = ap[2];
    ra = x * x + y * y + z * z;
    unsigned int hx, lx, hy, ly, hz, lz;
    bfsplit(x, hx, lx); bfsplit(y, hy, ly); bfsplit(z, hz, lz);
    const unsigned int one = 0x3F80u;
    if (l < 32) {   // k=0..7: (a_hi, 1, a_lo, 1)
        bf.u4 = make_uint4(pack2(hx, hy), pack2(hz, one),
                           pack2(lx, ly), pack2(lz, one));
    } else {        // k=8..15: (a_hi, 0, 0, 0)
        bf.u4 = make_uint4(pack2(hx, hy), pack2(hz, 0u), 0u, 0u);
    }
}

__device__ __forceinline__ float min16(const f32x16& D) {
    const float t0 = fminf(fminf(D[0],  D[1]),  D[2]);
    const float t1 = fminf(fminf(D[3],  D[4]),  D[5]);
    const float t2 = fminf(fminf(D[6],  D[7]),  D[8]);
    const float t3 = fminf(fminf(D[9],  D[10]), D[11]);
    const float t4 = fminf(fminf(D[12], D[13]), D[14]);
    const float u0 = fminf(fminf(t0, t1), t2);
    const float u1 = fminf(fminf(t3, t4), D[15]);
    return fminf(u0, u1);
}

// ---------------------------------------------------------------------------
// Pack kernel: write the A-operand frag stream once per b-point (the bytes
// previously rebuilt redundantly by every cd_main block in LDS):
//   point i, group g=i>>5, r=i&31: hi-frag at u4[g*64+r], lo-frag at
//   u4[g*64+32+r] — identical image to the old LDS layout, so cd_main's
//   lane read address formula is unchanged.
// blocks [0,64):   skel  (16384 pts; per-batch base b*4096 u4)
// blocks [64,320): shape (65536 pts; per-batch base b*16384 u4)
// ---------------------------------------------------------------------------
__global__ __launch_bounds__(256) void cd_pack(
    const float* __restrict__ shape, const float* __restrict__ skel,
    uint4* __restrict__ skel_pk, uint4* __restrict__ shape_pk)
{
    const int bid = blockIdx.x, tid = threadIdx.x;
    const float* q;
    uint4* dst;
    int g, r;
    if (bid < 64) {
        const int idx = bid * 256 + tid;          // [0, 16384)
        const int b = idx >> 11, i = idx & 2047;
        q = skel + ((size_t)b * SKEL_M + i) * 3;
        dst = skel_pk + (size_t)b * 4096;
        g = i >> 5; r = i & 31;
    } else {
        const int idx = (bid - 64) * 256 + tid;   // [0, 65536)
        const int b = idx >> 13, i = idx & 8191;
        q = shape + ((size_t)b * SHAPE_N + i) * 6;
        dst = shape_pk + (size_t)b * 16384;
        g = i >> 5; r = i & 31;
    }
    const float bx = q[0], by = q[1], bz = q[2];
    const float cx = -2.f * bx, cy = -2.f * by, cz = -2.f * bz;
    const float rb = bx * bx + by * by + bz * bz;
    unsigned int chx, clx, chy, cly, chz, clz, rbh, rbl;
    bfsplit(cx, chx, clx); bfsplit(cy, chy, cly); bfsplit(cz, chz, clz);
    bfsplit(rb, rbh, rbl);
    dst[g * 64 + r]      = make_uint4(pack2(chx, chy), pack2(chz, rbh),
                                      pack2(chx, chy), pack2(chz, rbl));
    dst[g * 64 + 32 + r] = make_uint4(pack2(clx, cly), pack2(clz, 0u), 0u, 0u);
}

// ---------------------------------------------------------------------------
// Scan 2048 packed b-points (64 steps) against this wave's 32 resident
// a-points, streaming frags straight from L2 — no LDS, no barriers.
// Wave load: lanes 0-31 read 512 B (hi half), lanes 32-63 the next 512 B
// (lo half) -> one fully-coalesced 1 KB global_load_dwordx4 per step.
// D[m][n] = rb_m - 2 b_m.a_n, hi/lo bf16 split over K=16 (bit-identical to
// the passing R7-R10 kernels); ra added in fp32 by the caller.
// ---------------------------------------------------------------------------
template <int SA>
__device__ __forceinline__ float cd_scan_g(
    const float* __restrict__ Araw,    // this wave's 32 a-points (stride SA)
    const uint4* __restrict__ pk,      // packed frag stream base (2048 pts)
    float& ra_out)
{
    const int l = threadIdx.x & 63;
    FragU bf;
    make_bfrag(Araw + (size_t)(l & 31) * SA, l, bf, ra_out);

    const f32x16 Z = {0,0,0,0,0,0,0,0,0,0,0,0,0,0,0,0};
    float rmin = 3.4e38f;
    const uint4* p = pk + ((l >> 5) * 32 + (l & 31));

#pragma unroll 4
    for (int g = 0; g < 64; ++g) {
        FragU af;
        af.u4 = p[(size_t)g * 64];
        f32x16 D = __builtin_amdgcn_mfma_f32_32x32x16_bf16(af.v, bf.v, Z, 0, 0, 0);
        rmin = fminf(rmin, min16(D));
    }
    // lane l and l^32 cover complementary rows of the same col (a-point)
    return fminf(rmin, __shfl_xor(rmin, 32, 64));
}

// ---------------------------------------------------------------------------
// 1024 blocks x 128 thr (2 waves), 8 waves/CU, every block exactly 64 steps:
//   [0,512):    dir1 — 128 shape a-pts, full skel stream. Complete min =>
//               sqrt + block-sum => part1[bid].
//   [512,1024): dir2 — 128 skel a-pts, one shape-quarter stream. Partial
//               min => plain stores into part2 quarter slice.
// ---------------------------------------------------------------------------
__global__ __launch_bounds__(128) void cd_main(
    const float* __restrict__ shape, const float* __restrict__ skel,
    const uint4* __restrict__ skel_pk, const uint4* __restrict__ shape_pk,
    float* __restrict__ part1, float* __restrict__ part2)
{
    __shared__ float s_wsum[2];
    const int tid = threadIdx.x;
    const int l = tid & 63, wv = tid >> 6;     // wv in {0,1}
    const int bid = blockIdx.x;

    if (bid < 512) {       // dir1: a = shape (stride 6), b = skel
        const int b = bid >> 6, sub = bid & 63;
        float ra;
        const float rmin = cd_scan_g<6>(
            shape + ((size_t)b * SHAPE_N + sub * 128 + wv * 64 + 0) * 6,
            skel_pk + (size_t)b * 4096, ra);
        // wave owns 64 a-pts? No: one frag = 32 a-pts; second 32 handled below
        float ra2;
        const float rmin2 = cd_scan_g<6>(
            shape + ((size_t)b * SHAPE_N + sub * 128 + wv * 64 + 32) * 6,
            skel_pk + (size_t)b * 4096, ra2);
        float d = (l < 32) ? sqrtf(fmaxf(ra + rmin, 0.f)) +
                             sqrtf(fmaxf(ra2 + rmin2, 0.f)) : 0.f;
        for (int o = 32; o; o >>= 1) d += __shfl_down(d, o, 64);
        if (l == 0) s_wsum[wv] = d;
        __syncthreads();
        if (tid == 0) part1[bid] = s_wsum[0] + s_wsum[1];
    } else {               // dir2: a = skel (stride 3), b = shape quarter
        const int j = bid - 512;
        const int b = j >> 6, rem = j & 63;    // 16 a-blocks x 4 quarters
        const int ablk = rem >> 2, q = rem & 3;
        const uint4* stream = shape_pk + (size_t)b * 16384 + (size_t)q * 4096;
        float ra, ra2;
        const float rmin = cd_scan_g<3>(
            skel + ((size_t)b * SKEL_M + ablk * 128 + wv * 64 + 0) * 3,
            stream, ra);
        const float rmin2 = cd_scan_g<3>(
            skel + ((size_t)b * SKEL_M + ablk * 128 + wv * 64 + 32) * 3,
            stream, ra2);
        if (l < 32) {
            float* w = part2 + (size_t)q * (BATCH * SKEL_M) + b * SKEL_M +
                       ablk * 128 + wv * 64;
            w[l]      = ra + rmin;
            w[32 + l] = ra2 + rmin2;
        }
    }
}

// ---------------------------------------------------------------------------
// Single-block reduce: min-fold the 4 dir2 quarters (float4 loads, 256 KB,
// L2-resident), clamp+sqrt+sum, add the 512 dir1 partials, write out[0].
// ---------------------------------------------------------------------------
__global__ __launch_bounds__(1024) void cd_reduce(
    const float* __restrict__ part1, const float* __restrict__ part2,
    float* __restrict__ out)
{
    __shared__ float s_wsum[16];
    const int t = threadIdx.x;
    float s = 0.f;

    const float4* w4 = (const float4*)part2;
#pragma unroll
    for (int r = 0; r < 4; ++r) {
        const int i4 = r * 1024 + t;          // float4 index within 4096
        float4 v0 = w4[i4];
        const float4 v1 = w4[4096 + i4];
        const float4 v2 = w4[8192 + i4];
        const float4 v3 = w4[12288 + i4];
        v0.x = fminf(fminf(v0.x, v1.x), fminf(v2.x, v3.x));
        v0.y = fminf(fminf(v0.y, v1.y), fminf(v2.y, v3.y));
        v0.z = fminf(fminf(v0.z, v1.z), fminf(v2.z, v3.z));
        v0.w = fminf(fminf(v0.w, v1.w), fminf(v2.w, v3.w));
        s += sqrtf(fmaxf(v0.x, 0.f)) + sqrtf(fmaxf(v0.y, 0.f)) +
             sqrtf(fmaxf(v0.z, 0.f)) + sqrtf(fmaxf(v0.w, 0.f));
    }
    if (t < 512) s += part1[t];               // dir1 per-block partial sums

    for (int o = 32; o; o >>= 1) s += __shfl_down(s, o, 64);
    const int lane = t & 63, wave = t >> 6;
    if (lane == 0) s_wsum[wave] = s;
    __syncthreads();
    if (t == 0) {
        float tot = 0.f;
#pragma unroll
        for (int w = 0; w < 16; ++w) tot += s_wsum[w];
        out[0] = tot * 1e-4f;
    }
}

extern "C" void kernel_launch(void* const* d_in, const int* in_sizes, int n_in,
                              void* d_out, int out_size, void* d_ws, size_t ws_size,
                              hipStream_t stream) {
    const float* shape = (const float*)d_in[0];   // (8, 8192, 6) — use first 3
    const float* skel  = (const float*)d_in[1];   // (8, 2048, 3)
    float* out         = (float*)d_out;           // scalar

    uint4* skel_pk  = (uint4*)d_ws;               // 32768 uint4  = 512 KB
    uint4* shape_pk = skel_pk + 32768;            // 131072 uint4 = 2 MB
    float* part1    = (float*)(shape_pk + 131072);// 512 floats
    float* part2    = part1 + 512;                // 65536 floats = 256 KB

    cd_pack<<<320, 256, 0, stream>>>(shape, skel, skel_pk, shape_pk);
    cd_main<<<1024, 128, 0, stream>>>(shape, skel, skel_pk, shape_pk,
                                      part1, part2);
    cd_reduce<<<1, 1024, 0, stream>>>(part1, part2, out);
}

// Round 12
// 76.714 us; speedup vs baseline: 1.2589x; 1.2589x over previous
//
#include <hip/hip_runtime.h>

#define BATCH   8
#define SHAPE_N 8192
#define SKEL_M  2048
#define CHUNK   1024   // b-points per LDS chunk: 1024 pts * 32 B = 32 KB

// ws layout:
//   uint4[0,      32768): packed skel  frags (16384 pts x 2 uint4)  512 KB
//   uint4[32768, 163840): packed shape frags (65536 pts x 2 uint4)    2 MB
//   float part1[512]                  dir1 per-block partial sums
//   float part2[4][8][2048]           dir2 partial mins (quarter-major)
// Every slot read is written in the same iteration -> re-poison-safe,
// no init, no atomics.

// MFMA frag types (gfx950: 32x32x16 bf16 — A/B = 8 bf16 (4 VGPRs), C/D = 16 f32)
typedef short bf16x8 __attribute__((ext_vector_type(8)));
typedef float f32x16 __attribute__((ext_vector_type(16)));
union FragU { bf16x8 v; uint4 u4; };

// round-to-nearest-even f32 -> bf16 (result in low 16 bits)
__device__ __forceinline__ unsigned int f2bf(float a) {
    unsigned int u = __float_as_uint(a);
    return (u + 0x7FFFu + ((u >> 16) & 1u)) >> 16;
}
__device__ __forceinline__ float bf2f(unsigned int h) {
    return __uint_as_float(h << 16);
}
__device__ __forceinline__ unsigned int pack2(unsigned int lo, unsigned int hi) {
    return lo | (hi << 16);
}
// v ~= hi + lo (two bf16), residual ~2^-16 relative
__device__ __forceinline__ void bfsplit(float v, unsigned int& h, unsigned int& l) {
    h = f2bf(v);
    l = f2bf(v - bf2f(h));
}

// resident B-operand frag + fp32 |a|^2 for one a-point (same as R7-R11)
__device__ __forceinline__ void make_bfrag(
    const float* __restrict__ ap, int l, FragU& bf, float& ra)
{
    const float x = ap[0], y = ap[1], z = ap[2];
    ra = x * x + y * y + z * z;
    unsigned int hx, lx, hy, ly, hz, lz;
    bfsplit(x, hx, lx); bfsplit(y, hy, ly); bfsplit(z, hz, lz);
    const unsigned int one = 0x3F80u;
    if (l < 32) {   // k=0..7: (a_hi, 1, a_lo, 1)
        bf.u4 = make_uint4(pack2(hx, hy), pack2(hz, one),
                           pack2(lx, ly), pack2(lz, one));
    } else {        // k=8..15: (a_hi, 0, 0, 0)
        bf.u4 = make_uint4(pack2(hx, hy), pack2(hz, 0u), 0u, 0u);
    }
}

__device__ __forceinline__ float min16(const f32x16& D) {
    const float t0 = fminf(fminf(D[0],  D[1]),  D[2]);
    const float t1 = fminf(fminf(D[3],  D[4]),  D[5]);
    const float t2 = fminf(fminf(D[6],  D[7]),  D[8]);
    const float t3 = fminf(fminf(D[9],  D[10]), D[11]);
    const float t4 = fminf(fminf(D[12], D[13]), D[14]);
    const float u0 = fminf(fminf(t0, t1), t2);
    const float u1 = fminf(fminf(t3, t4), D[15]);
    return fminf(u0, u1);
}

// ---------------------------------------------------------------------------
// Pack kernel: build the A-operand frag stream ONCE per b-point (these bytes
// were previously rebuilt redundantly by every cd_main block). Image per
// batch: groups g=i>>5 of 64 uint4 (32 hi-frags then 32 lo-frags) — chunk c
// of 1024 pts is the contiguous uint4 range [c*2048, (c+1)*2048).
// blocks [0,64):   skel  (16384 pts; per-batch base b*4096 u4)
// blocks [64,320): shape (65536 pts; per-batch base b*16384 u4)
// ---------------------------------------------------------------------------
__global__ __launch_bounds__(256) void cd_pack(
    const float* __restrict__ shape, const float* __restrict__ skel,
    uint4* __restrict__ skel_pk, uint4* __restrict__ shape_pk)
{
    const int bid = blockIdx.x, tid = threadIdx.x;
    const float* q;
    uint4* dst;
    int g, r;
    if (bid < 64) {
        const int idx = bid * 256 + tid;          // [0, 16384)
        const int b = idx >> 11, i = idx & 2047;
        q = skel + ((size_t)b * SKEL_M + i) * 3;
        dst = skel_pk + (size_t)b * 4096;
        g = i >> 5; r = i & 31;
    } else {
        const int idx = (bid - 64) * 256 + tid;   // [0, 65536)
        const int b = idx >> 13, i = idx & 8191;
        q = shape + ((size_t)b * SHAPE_N + i) * 6;
        dst = shape_pk + (size_t)b * 16384;
        g = i >> 5; r = i & 31;
    }
    const float bx = q[0], by = q[1], bz = q[2];
    const float cx = -2.f * bx, cy = -2.f * by, cz = -2.f * bz;
    const float rb = bx * bx + by * by + bz * bz;
    unsigned int chx, clx, chy, cly, chz, clz, rbh, rbl;
    bfsplit(cx, chx, clx); bfsplit(cy, chy, cly); bfsplit(cz, chz, clz);
    bfsplit(rb, rbh, rbl);
    dst[g * 64 + r]      = make_uint4(pack2(chx, chy), pack2(chz, rbh),
                                      pack2(chx, chy), pack2(chz, rbl));
    dst[g * 64 + 32 + r] = make_uint4(pack2(clx, cly), pack2(clz, 0u), 0u, 0u);
}

// ---------------------------------------------------------------------------
// Scan 2048 packed b-points against this wave's 32 resident a-points.
// Staging per 1024-pt chunk is a pure coalesced copy (8 uint4 loads +
// 8 ds_writes per thread) of the pre-packed stream — no per-block repack.
// Inner loop identical to R9 (best): 1 ds_read_b128 -> 1 MFMA -> min tree.
// ---------------------------------------------------------------------------
template <int SA>
__device__ __forceinline__ float cd_scan(
    const float* __restrict__ Araw,    // this wave's 32 a-points (stride SA)
    const uint4* __restrict__ pk,      // packed 2048-pt frag stream
    uint4* sB, float& ra_out)
{
    const int tid = threadIdx.x;
    const int l = tid & 63;

    FragU bf;
    make_bfrag(Araw + (size_t)(l & 31) * SA, l, bf, ra_out);

    const f32x16 Z = {0,0,0,0,0,0,0,0,0,0,0,0,0,0,0,0};
    float rmin = 3.4e38f;
    const unsigned int off0 = (unsigned int)((l >> 5) * 512 + (l & 31) * 16);

    for (int c = 0; c < 2; ++c) {
        __syncthreads();                       // previous chunk fully consumed
        const uint4* src = pk + (size_t)c * 2048;
#pragma unroll
        for (int k = 0; k < 2048; k += 256)
            sB[k + tid] = src[k + tid];
        __syncthreads();

        unsigned int o = off0;
#pragma unroll 8
        for (int g = 0; g < CHUNK / 32; ++g) {
            FragU af;
            af.u4 = *(const uint4*)((const char*)sB + o);
            o += 1024;
            f32x16 D = __builtin_amdgcn_mfma_f32_32x32x16_bf16(af.v, bf.v, Z, 0, 0, 0);
            rmin = fminf(rmin, min16(D));
        }
    }
    // lane l and l^32 cover complementary rows of the same col (a-point)
    return fminf(rmin, __shfl_xor(rmin, 32, 64));
}

// ---------------------------------------------------------------------------
// 1024 equal blocks (64 MFMA steps each), 4 blocks/CU, 16 waves/CU — R9
// geometry:
//   [0,512):    dir1 — a = shape (128 pts/block), b = full skel stream.
//               Complete min => sqrt + block-sum => part1[bid].
//   [512,1024): dir2 — a = skel (128 pts/block), b = one shape-quarter
//               stream. Partial min => plain stores into part2 slice.
// ---------------------------------------------------------------------------
__global__ __launch_bounds__(256) void cd_main(
    const float* __restrict__ shape, const float* __restrict__ skel,
    const uint4* __restrict__ skel_pk, const uint4* __restrict__ shape_pk,
    float* __restrict__ part1, float* __restrict__ part2)
{
    __shared__ uint4 sB[CHUNK * 2];    // 32 KB
    __shared__ float s_wsum[4];
    const int tid = threadIdx.x;
    const int l = tid & 63, wv = tid >> 6;
    const int bid = blockIdx.x;

    if (bid < 512) {                   // dir1: a = shape (stride 6), b = skel
        const int b = bid >> 6, sub = bid & 63;
        float ra;
        const float rmin = cd_scan<6>(
            shape + ((size_t)b * SHAPE_N + sub * 128 + wv * 32) * 6,
            skel_pk + (size_t)b * 4096, sB, ra);
        float d = (l < 32) ? sqrtf(fmaxf(ra + rmin, 0.f)) : 0.f;
        for (int o = 32; o; o >>= 1) d += __shfl_down(d, o, 64);
        if (l == 0) s_wsum[wv] = d;
        __syncthreads();
        if (tid == 0)
            part1[bid] = s_wsum[0] + s_wsum[1] + s_wsum[2] + s_wsum[3];
    } else {                           // dir2: a = skel (stride 3), b = shape quarter
        const int j = bid - 512;
        const int b = j >> 6, rem = j & 63;
        const int asub = rem >> 2, q = rem & 3;
        float ra;
        const float rmin = cd_scan<3>(
            skel + ((size_t)b * SKEL_M + asub * 128 + wv * 32) * 3,
            shape_pk + (size_t)b * 16384 + (size_t)q * 4096, sB, ra);
        if (l < 32)
            part2[(size_t)q * (BATCH * SKEL_M) + b * SKEL_M +
                  asub * 128 + wv * 32 + l] = ra + rmin;
    }
}

// ---------------------------------------------------------------------------
// Single-block reduce: min-fold the 4 dir2 quarters (float4 loads, 256 KB,
// L2-resident), clamp+sqrt+sum, add the 512 dir1 partials, write out[0].
// ---------------------------------------------------------------------------
__global__ __launch_bounds__(1024) void cd_reduce(
    const float* __restrict__ part1, const float* __restrict__ part2,
    float* __restrict__ out)
{
    __shared__ float s_wsum[16];
    const int t = threadIdx.x;
    float s = 0.f;

    const float4* w4 = (const float4*)part2;
#pragma unroll
    for (int r = 0; r < 4; ++r) {
        const int i4 = r * 1024 + t;          // float4 index within 4096
        float4 v0 = w4[i4];
        const float4 v1 = w4[4096 + i4];
        const float4 v2 = w4[8192 + i4];
        const float4 v3 = w4[12288 + i4];
        v0.x = fminf(fminf(v0.x, v1.x), fminf(v2.x, v3.x));
        v0.y = fminf(fminf(v0.y, v1.y), fminf(v2.y, v3.y));
        v0.z = fminf(fminf(v0.z, v1.z), fminf(v2.z, v3.z));
        v0.w = fminf(fminf(v0.w, v1.w), fminf(v2.w, v3.w));
        s += sqrtf(fmaxf(v0.x, 0.f)) + sqrtf(fmaxf(v0.y, 0.f)) +
             sqrtf(fmaxf(v0.z, 0.f)) + sqrtf(fmaxf(v0.w, 0.f));
    }
    if (t < 512) s += part1[t];               // dir1 per-block partial sums

    for (int o = 32; o; o >>= 1) s += __shfl_down(s, o, 64);
    const int lane = t & 63, wave = t >> 6;
    if (lane == 0) s_wsum[wave] = s;
    __syncthreads();
    if (t == 0) {
        float tot = 0.f;
#pragma unroll
        for (int w = 0; w < 16; ++w) tot += s_wsum[w];
        out[0] = tot * 1e-4f;
    }
}

extern "C" void kernel_launch(void* const* d_in, const int* in_sizes, int n_in,
                              void* d_out, int out_size, void* d_ws, size_t ws_size,
                              hipStream_t stream) {
    const float* shape = (const float*)d_in[0];   // (8, 8192, 6) — use first 3
    const float* skel  = (const float*)d_in[1];   // (8, 2048, 3)
    float* out         = (float*)d_out;           // scalar

    uint4* skel_pk  = (uint4*)d_ws;               // 32768 uint4  = 512 KB
    uint4* shape_pk = skel_pk + 32768;            // 131072 uint4 = 2 MB
    float* part1    = (float*)(shape_pk + 131072);// 512 floats
    float* part2    = part1 + 512;                // 65536 floats = 256 KB

    cd_pack<<<320, 256, 0, stream>>>(shape, skel, skel_pk, shape_pk);
    cd_main<<<1024, 256, 0, stream>>>(shape, skel, skel_pk, shape_pk,
                                      part1, part2);
    cd_reduce<<<1, 1024, 0, stream>>>(part1, part2, out);
}